// Round 11
// baseline (408.641 us; speedup 1.0000x reference)
//
#include <hip/hip_runtime.h>

#define NN 32768
#define KK 16
#define DD 6
// State row per node-slot j: 64 x uint2 {hg, c} = 512 B interleaved.
//   .x = (int16)(h*32767) | (int16)(g*2048) << 16      .y = c as fp32 bits
// Row 0 = all zero (child_idx==0 masking is free).
// Wx (per-depth ping-pong buffer, fp16, MFMA C-FRAGMENT layout):
//   [block b][wave wv][tile nt(16)][lane ln(64)][reg r(4)]
//   element = gate-col nt*16+(ln&15), node b*64+(ln>>4)*4+r (+wv*16).

typedef short short8 __attribute__((ext_vector_type(8)));
typedef float floatx4 __attribute__((ext_vector_type(4)));
typedef _Float16 half4v __attribute__((ext_vector_type(4)));

__device__ __forceinline__ float sigm(float x) { return 1.0f / (1.0f + __expf(-x)); }
__device__ __forceinline__ float ftanh(float x) {
    float e = __expf(2.0f * x);
    return 1.0f - 2.0f / (e + 1.0f);
}
__device__ __forceinline__ unsigned short f2bf(float x) {   // RNE fp32->bf16
    union { float f; unsigned u; } v; v.f = x;
    unsigned r = v.u + 0x7FFF + ((v.u >> 16) & 1);
    return (unsigned short)(r >> 16);
}
__device__ __forceinline__ float bf2f(unsigned short h) {
    union { unsigned u; float f; } v; v.u = ((unsigned)h) << 16; return v.f;
}

// ---------------------------------------------------------------------------
// wx producer (device fn): WxF[blk] = frag(E[labels] @ W_w + W_b) for one
// 64-node block of one depth. lds overlay: Ax[64][74]@0, Bw[256][74]@64*74,
// labs(int[64])@320*74. 47,616 B total. Fragment stores: 16 x dwordx2/lane.
__device__ __forceinline__ void wx_role(
    const int* __restrict__ labels, const float* __restrict__ E,
    const float* __restrict__ W_w, const float* __restrict__ W_b,
    _Float16* __restrict__ WxF, int blk, unsigned short* lds)
{
    unsigned short (*Ax)[74] = (unsigned short(*)[74])lds;
    unsigned short (*Bw)[74] = (unsigned short(*)[74])(lds + 64 * 74);
    int* labs = (int*)(lds + 320 * 74);
    const int tid = threadIdx.x;
    const int n0 = blk * 64;
    if (tid < 64) labs[tid] = labels[n0 + tid];
    __syncthreads();
    {   // stage A: thread -> node m = tid>>2, 16 dims
        const int m = tid >> 2, q = tid & 3;
        const float4* e4 = (const float4*)(E + (size_t)labs[m] * 64 + q * 16);
#pragma unroll
        for (int i = 0; i < 4; ++i) {
            float4 v = e4[i];
            Ax[m][q * 16 + i * 4 + 0] = f2bf(v.x);
            Ax[m][q * 16 + i * 4 + 1] = f2bf(v.y);
            Ax[m][q * 16 + i * 4 + 2] = f2bf(v.z);
            Ax[m][q * 16 + i * 4 + 3] = f2bf(v.w);
        }
    }
    {   // stage B transposed: thread = col, coalesced global reads per k
        const int c = tid;
#pragma unroll 4
        for (int k = 0; k < 64; ++k) Bw[c][k] = f2bf(W_w[k * 256 + c]);
    }
    __syncthreads();
    const int ln = tid & 63, wv = tid >> 6;
    const int lr = ln & 15, qd = ln >> 4;
    short8 af[2];
#pragma unroll
    for (int ks = 0; ks < 2; ++ks)
        af[ks] = *(const short8*)&Ax[wv * 16 + lr][ks * 32 + qd * 8];
    floatx4 acc[16];
#pragma unroll
    for (int nt = 0; nt < 16; ++nt) acc[nt] = (floatx4){0.f, 0.f, 0.f, 0.f};
#pragma unroll
    for (int nt = 0; nt < 16; ++nt) {
#pragma unroll
        for (int ks = 0; ks < 2; ++ks) {
            short8 bw = *(const short8*)&Bw[nt * 16 + lr][ks * 32 + qd * 8];
            acc[nt] = __builtin_amdgcn_mfma_f32_16x16x32_bf16(af[ks], bw, acc[nt], 0, 0, 0);
        }
    }
    _Float16* __restrict__ base =
        WxF + ((size_t)blk * 4 + wv) * 16 * 256 + (size_t)ln * 4;
#pragma unroll
    for (int nt = 0; nt < 16; ++nt) {
        const float bb = W_b[nt * 16 + lr];
        half4v hv;
#pragma unroll
        for (int r = 0; r < 4; ++r) hv[r] = (_Float16)(acc[nt][r] + bb);
        *(half4v*)&base[nt * 256] = hv;
    }
}

// K0_ONE: seeds Wx for depth 0 (512 blocks).
__global__ __launch_bounds__(256) void k0_one(
    const int* __restrict__ labels, const float* __restrict__ E,
    const float* __restrict__ W_w, const float* __restrict__ W_b,
    _Float16* __restrict__ Wx)
{
    __shared__ __align__(16) unsigned short lds[23808];   // 47,616 B
    wx_role(labels, E, W_w, W_b, Wx, blockIdx.x, lds);
}

// ---------------------------------------------------------------------------
// KD: gather (simple loop, 2 k-steps batched per wait -- R10's interleaved
// pipeline regressed 49->59 us: compiler vmcnt(0) made each consume wait on
// the OTHER batch's fresh loads) + iuo-GEMM + gates + g-GEMM + pack store,
// THEN (same block, after barrier, LDS overlaid) the wx producer for depth
// d+1's same 64 nodes -- fills this block's own idle issue slots, no R9
// role-block dispatch hazard. LDS 52,224 B.
__global__ __launch_bounds__(256) void kd_fused(
    const int* __restrict__ cidx, const uint2* __restrict__ sprev,
    const _Float16* __restrict__ Wx, _Float16* __restrict__ WxNext,
    const int* __restrict__ labels_next, const float* __restrict__ E,
    const float* __restrict__ W_w, const float* __restrict__ W_b,
    const float* __restrict__ U_iuo, const float* __restrict__ U_f,
    uint2* __restrict__ snext, float* __restrict__ out, int first, int last)
{
    __shared__ __align__(16) unsigned short LDS[26112];   // 52,224 B
    unsigned short (*Bi)[68]   = (unsigned short(*)[68])LDS;             // U_iuo^T
    unsigned short (*Bf)[68]   = (unsigned short(*)[68])(LDS + 192*68);  // U_f^T
    unsigned short (*Ah)[68]   = (unsigned short(*)[68])(LDS + 256*68);  // hsum hi
    unsigned short (*AlHs)[68] = (unsigned short(*)[68])(LDS + 320*68);  // lo / nh
    const int tid = threadIdx.x;
    const int n0 = blockIdx.x * 64;
    if (tid < 192) {
        const int c = tid;
#pragma unroll 4
        for (int k = 0; k < 64; ++k) Bi[c][k] = f2bf(U_iuo[k * 192 + c]);
    } else {
        const int c = tid - 192;
#pragma unroll 4
        for (int k = 0; k < 64; ++k) Bf[c][k] = f2bf(U_f[k * 64 + c]);
    }
    const int ln = tid & 63, wv = tid >> 6;
    const int lr = ln & 15, qd = ln >> 4;
    const _Float16* __restrict__ wbase =
        Wx + ((size_t)blockIdx.x * 4 + wv) * 16 * 256 + (size_t)ln * 4;

    // ---- gather phase: hs/bf in C-layout registers, 2 k-steps per wait
    float hs[4][4] = {{0.f}}, bfv[4][4] = {{0.f}};
    if (!first) {
        float wfx[4][4];
#pragma unroll
        for (int nt = 0; nt < 4; ++nt) {                     // f tiles 0..3
            const half4v fv = *(const half4v*)&wbase[nt * 256];
#pragma unroll
            for (int r = 0; r < 4; ++r) wfx[r][nt] = (float)fv[r];
        }
        const size_t cb = (size_t)(n0 + wv * 16 + qd * 4) * KK;
        auto consume = [&](uint2 (&v)[4][4]) {
#pragma unroll
            for (int r = 0; r < 4; ++r)
#pragma unroll
                for (int nt = 0; nt < 4; ++nt) {
                    const float h = (float)(short)(v[r][nt].x & 0xFFFFu) * (1.f / 32767.f);
                    const float g = (float)((int)v[r][nt].x >> 16) * (1.f / 2048.f);
                    const float c = __uint_as_float(v[r][nt].y);
                    hs[r][nt] += h;
                    bfv[r][nt] = fmaf(sigm(wfx[r][nt] + g), c, bfv[r][nt]);
                }
        };
#pragma unroll 1
        for (int k = 0; k < KK; k += 2) {
            int id0[4], id1[4];
#pragma unroll
            for (int r = 0; r < 4; ++r) id0[r] = cidx[cb + r * KK + k];
#pragma unroll
            for (int r = 0; r < 4; ++r) id1[r] = cidx[cb + r * KK + k + 1];
            uint2 va[4][4], vb[4][4];
#pragma unroll
            for (int r = 0; r < 4; ++r)
#pragma unroll
                for (int nt = 0; nt < 4; ++nt)
                    va[r][nt] = sprev[(size_t)id0[r] * 64 + nt * 16 + lr];
#pragma unroll
            for (int r = 0; r < 4; ++r)
#pragma unroll
                for (int nt = 0; nt < 4; ++nt)
                    vb[r][nt] = sprev[(size_t)id1[r] * 64 + nt * 16 + lr];
            consume(va);    // one waitcnt covers both 16-load batches
            consume(vb);
        }
    }
    // ---- hsum -> LDS A-tile, split hi/lo bf16 (|hs|<=16 precision-critical)
#pragma unroll
    for (int r = 0; r < 4; ++r)
#pragma unroll
        for (int nt = 0; nt < 4; ++nt) {
            const int m = wv * 16 + qd * 4 + r, col = nt * 16 + lr;
            const unsigned short hi = f2bf(hs[r][nt]);
            Ah[m][col] = hi;
            AlHs[m][col] = f2bf(hs[r][nt] - bf2f(hi));
        }
    __syncthreads();
    short8 ah[2], al[2];
#pragma unroll
    for (int ks = 0; ks < 2; ++ks) {
        ah[ks] = *(const short8*)&Ah[wv * 16 + lr][ks * 32 + qd * 8];
        al[ks] = *(const short8*)&AlHs[wv * 16 + lr][ks * 32 + qd * 8];
    }
    // ---- iuo GEMM: acc = hsum @ U_iuo (split-bf16 A, fp32 acc), 12 out-tiles
    floatx4 acc[12];
#pragma unroll
    for (int nt = 0; nt < 12; ++nt) {
        floatx4 a = (floatx4){0.f, 0.f, 0.f, 0.f};
#pragma unroll
        for (int ks = 0; ks < 2; ++ks) {
            const short8 bu = *(const short8*)&Bi[nt * 16 + lr][ks * 32 + qd * 8];
            a = __builtin_amdgcn_mfma_f32_16x16x32_bf16(al[ks], bu, a, 0, 0, 0);
            a = __builtin_amdgcn_mfma_f32_16x16x32_bf16(ah[ks], bu, a, 0, 0, 0);
        }
        acc[nt] = a;
    }
    // ---- gate epilogue: i/u/o Wx tiles are dwordx2 fragment loads
    float nhv[4][4], ncv[4][4];
#pragma unroll
    for (int nt = 0; nt < 4; ++nt) {
        const int col = nt * 16 + lr;
        const half4v iv = *(const half4v*)&wbase[(4 + nt) * 256];
        const half4v uv = *(const half4v*)&wbase[(8 + nt) * 256];
        const half4v ov = *(const half4v*)&wbase[(12 + nt) * 256];
#pragma unroll
        for (int r = 0; r < 4; ++r) {
            const int node = n0 + wv * 16 + qd * 4 + r;
            const float ig = sigm(acc[nt][r] + (float)iv[r]);
            const float ug = ftanh(acc[4 + nt][r] + (float)uv[r]);
            const float og = sigm(acc[8 + nt][r] + (float)ov[r]);
            const float nc = fmaf(ig, ug, bfv[r][nt]);
            const float nh = og * ftanh(nc);
            nhv[nt][r] = nh;
            ncv[nt][r] = nc;
            if (last) {
                out[(size_t)node * 64 + col] = nh;
            } else {
                AlHs[wv * 16 + qd * 4 + r][col] = f2bf(nh);  // Al dead: restage nh
            }
        }
    }
    if (!last) {
        // ---- g = nh @ U_f (wave-private LDS tile; lgkmcnt covers the dep)
        short8 ag[2];
#pragma unroll
        for (int ks = 0; ks < 2; ++ks)
            ag[ks] = *(const short8*)&AlHs[wv * 16 + lr][ks * 32 + qd * 8];
        floatx4 g[4];
#pragma unroll
        for (int nt = 0; nt < 4; ++nt) {
            g[nt] = (floatx4){0.f, 0.f, 0.f, 0.f};
#pragma unroll
            for (int ks = 0; ks < 2; ++ks) {
                const short8 bfr = *(const short8*)&Bf[nt * 16 + lr][ks * 32 + qd * 8];
                g[nt] = __builtin_amdgcn_mfma_f32_16x16x32_bf16(ag[ks], bfr, g[nt], 0, 0, 0);
            }
        }
#pragma unroll
        for (int nt = 0; nt < 4; ++nt) {
#pragma unroll
            for (int r = 0; r < 4; ++r) {
                const int node = n0 + wv * 16 + qd * 4 + r;
                // |nh|<1 (o*tanh), |g|<=8 (64 * 1 * 0.125) -> int16 scales safe
                const int hq = (int)rintf(nhv[nt][r] * 32767.f);
                const int gq = (int)rintf(g[nt][r] * 2048.f);
                uint2 pw;
                pw.x = ((unsigned)hq & 0xFFFFu) | ((unsigned)gq << 16);
                pw.y = __float_as_uint(ncv[nt][r]);
                snext[(size_t)(node + 1) * 64 + nt * 16 + lr] = pw;
            }
        }
        if (blockIdx.x == 0 && tid < 64)
            snext[tid] = make_uint2(0u, 0u);   // zero init-state row

        // ---- wx tail: produce Wx[d+1] for this block's nodes. Barrier, then
        // overlay wx LDS (47,616 B) on the dead Bi/Bf/Ah/AlHs region.
        __syncthreads();
        wx_role(labels_next, E, W_w, W_b, WxNext, blockIdx.x, LDS);
    }
}

extern "C" void kernel_launch(void* const* d_in, const int* in_sizes, int n_in,
                              void* d_out, int out_size, void* d_ws, size_t ws_size,
                              hipStream_t stream)
{
    const int*   labels = (const int*)d_in[0];    // [6, 32768]
    const int*   child  = (const int*)d_in[1];    // [6, 32768, 16]
    const float* E      = (const float*)d_in[2];  // [100000, 64]
    const float* W_w    = (const float*)d_in[3];  // [64, 256]
    const float* W_b    = (const float*)d_in[4];  // [256]
    const float* U_f    = (const float*)d_in[5];  // [64, 64]
    const float* U_iuo  = (const float*)d_in[6];  // [64, 192]
    float* out = (float*)d_out;

    // ws: s0,s1 state ping-pong ((NN+1)*512 B = 16.8 MB each);
    //     wA,wB Wx fragment ping-pong (NN*256 fp16 = 16.8 MB each). ~67 MB.
    uint2* s0 = (uint2*)d_ws;
    uint2* s1 = s0 + (size_t)(NN + 1) * 64;
    _Float16* wA = (_Float16*)(s1 + (size_t)(NN + 1) * 64);
    _Float16* wB = wA + (size_t)NN * 256;

    k0_one<<<512, 256, 0, stream>>>(labels, E, W_w, W_b, wA);  // seed Wx[0]

    uint2* sp = s0;
    uint2* sn = s1;
    for (int d = 0; d < DD; ++d) {
        const int last = (d == DD - 1);
        _Float16* wc = (d & 1) ? wB : wA;
        _Float16* wn = (d & 1) ? wA : wB;
        const int* lnext = labels + (size_t)(last ? d : d + 1) * NN;
        kd_fused<<<NN / 64, 256, 0, stream>>>(
            child + (size_t)d * NN * KK, sp, wc, wn, lnext,
            E, W_w, W_b, U_iuo, U_f, sn, out, d == 0, last);
        uint2* ts = sp; sp = sn; sn = ts;
    }
}

// Round 12
// 358.346 us; speedup vs baseline: 1.1404x; 1.1404x over previous
//
#include <hip/hip_runtime.h>

#define NN 32768
#define KK 16
#define DD 6
// State row per node-slot j: 64 x uint2 {hg, c} = 512 B interleaved.
//   .x = (int16)(h*32767) | (int16)(g*2048) << 16      .y = c as fp32 bits
// Row 0 = all zero (child_idx==0 masking is free).
// WxF: fp16 pre-activations in MFMA C-FRAGMENT layout:
//   [dep][block b][wave wv][tile nt(16)][lane ln(64)][reg r(4)]
//   element = gate-col nt*16+(ln&15), node b*64+wv*16+(ln>>4)*4+r.

typedef short short8 __attribute__((ext_vector_type(8)));
typedef float floatx4 __attribute__((ext_vector_type(4)));
typedef _Float16 half4v __attribute__((ext_vector_type(4)));

__device__ __forceinline__ float sigm(float x) { return 1.0f / (1.0f + __expf(-x)); }
__device__ __forceinline__ float ftanh(float x) {
    float e = __expf(2.0f * x);
    return 1.0f - 2.0f / (e + 1.0f);
}
__device__ __forceinline__ unsigned short f2bf(float x) {   // RNE fp32->bf16
    union { float f; unsigned u; } v; v.f = x;
    unsigned r = v.u + 0x7FFF + ((v.u >> 16) & 1);
    return (unsigned short)(r >> 16);
}
__device__ __forceinline__ float bf2f(unsigned short h) {
    union { unsigned u; float f; } v; v.u = ((unsigned)h) << 16; return v.f;
}

// ---------------------------------------------------------------------------
// K0_ALL (MFMA): WxF[dep][n-block] = frag(E[labels] @ W_w + W_b), all 6 depths
// in one launch (R8/R10-proven: 12 blocks/CU, HW co-schedules it efficiently;
// fragment-layout dwordx2 stores dropped it out of the top-5 in R10).
__global__ __launch_bounds__(256) void k0_all(
    const int* __restrict__ labels, const float* __restrict__ E,
    const float* __restrict__ W_w, const float* __restrict__ W_b,
    _Float16* __restrict__ WxF)
{
    __shared__ int labs[64];
    __shared__ __align__(16) unsigned short Ax[64][74];
    __shared__ __align__(16) unsigned short Bw[256][74];
    const int tid = threadIdx.x;
    const int blk = blockIdx.x & 511;
    const int dep = blockIdx.x >> 9;
    const int n0 = blk * 64;
    if (tid < 64) labs[tid] = labels[(size_t)dep * NN + n0 + tid];
    __syncthreads();
    {   // stage A: thread -> node m = tid>>2, 16 dims
        const int m = tid >> 2, q = tid & 3;
        const float4* e4 = (const float4*)(E + (size_t)labs[m] * 64 + q * 16);
#pragma unroll
        for (int i = 0; i < 4; ++i) {
            float4 v = e4[i];
            Ax[m][q * 16 + i * 4 + 0] = f2bf(v.x);
            Ax[m][q * 16 + i * 4 + 1] = f2bf(v.y);
            Ax[m][q * 16 + i * 4 + 2] = f2bf(v.z);
            Ax[m][q * 16 + i * 4 + 3] = f2bf(v.w);
        }
    }
    {   // stage B transposed: thread = col, coalesced global reads per k
        const int c = tid;
#pragma unroll 4
        for (int k = 0; k < 64; ++k) Bw[c][k] = f2bf(W_w[k * 256 + c]);
    }
    __syncthreads();
    const int ln = tid & 63, wv = tid >> 6;
    const int lr = ln & 15, qd = ln >> 4;
    short8 af[2];
#pragma unroll
    for (int ks = 0; ks < 2; ++ks)
        af[ks] = *(const short8*)&Ax[wv * 16 + lr][ks * 32 + qd * 8];
    floatx4 acc[16];
#pragma unroll
    for (int nt = 0; nt < 16; ++nt) acc[nt] = (floatx4){0.f, 0.f, 0.f, 0.f};
#pragma unroll
    for (int nt = 0; nt < 16; ++nt) {
#pragma unroll
        for (int ks = 0; ks < 2; ++ks) {
            short8 bw = *(const short8*)&Bw[nt * 16 + lr][ks * 32 + qd * 8];
            acc[nt] = __builtin_amdgcn_mfma_f32_16x16x32_bf16(af[ks], bw, acc[nt], 0, 0, 0);
        }
    }
    // fragment-layout store: 16 x dwordx2, coalesced (|preact|<10 -> fp16 ok)
    _Float16* __restrict__ base =
        WxF + ((size_t)(dep * 512 + blk) * 4 + wv) * 16 * 256 + (size_t)ln * 4;
#pragma unroll
    for (int nt = 0; nt < 16; ++nt) {
        const float bb = W_b[nt * 16 + lr];
        half4v hv;
#pragma unroll
        for (int r = 0; r < 4; ++r) hv[r] = (_Float16)(acc[nt][r] + bb);
        *(half4v*)&base[nt * 256] = hv;
    }
}

// ---------------------------------------------------------------------------
// KD: R8-proven simple gather loop + 1-deep ID prefetch (ids for k+1 issued
// before consuming k: the conservative vmcnt(0) at consume covers them, so
// the next iteration's data loads issue with no id wait -- removes the
// id->data serial latency from the critical path). R10's 2-deep data pipeline
// REGRESSED (49->59us: its prefetch load sat after the other batch's issue,
// so the id wait drained everything). Fragment Wx loads (dwordx2).
// No wx tail -- R11 proved post-barrier work adds full latency, hides nothing.
__global__ __launch_bounds__(256) void kd_fused(
    const int* __restrict__ cidx, const uint2* __restrict__ sprev,
    const _Float16* __restrict__ Wx, const float* __restrict__ U_iuo,
    const float* __restrict__ U_f, uint2* __restrict__ snext,
    float* __restrict__ out, int first, int last)
{
    __shared__ __align__(16) unsigned short Bi[192][68];   // U_iuo^T [c][k]
    __shared__ __align__(16) unsigned short Bf[64][68];    // U_f^T   [c][k]
    __shared__ __align__(16) unsigned short Ah[64][68];    // hsum hi
    __shared__ __align__(16) unsigned short AlHs[64][68];  // hsum lo, later nh
    const int tid = threadIdx.x;
    const int n0 = blockIdx.x * 64;
    if (tid < 192) {
        const int c = tid;
#pragma unroll 4
        for (int k = 0; k < 64; ++k) Bi[c][k] = f2bf(U_iuo[k * 192 + c]);
    } else {
        const int c = tid - 192;
#pragma unroll 4
        for (int k = 0; k < 64; ++k) Bf[c][k] = f2bf(U_f[k * 64 + c]);
    }
    const int ln = tid & 63, wv = tid >> 6;
    const int lr = ln & 15, qd = ln >> 4;
    const _Float16* __restrict__ wbase =
        Wx + ((size_t)blockIdx.x * 4 + wv) * 16 * 256 + (size_t)ln * 4;

    // ---- gather phase: hs/bf in C-layout registers, id-prefetched
    float hs[4][4] = {{0.f}}, bfv[4][4] = {{0.f}};
    if (!first) {
        float wfx[4][4];
#pragma unroll
        for (int nt = 0; nt < 4; ++nt) {                     // f tiles 0..3
            const half4v fv = *(const half4v*)&wbase[nt * 256];
#pragma unroll
            for (int r = 0; r < 4; ++r) wfx[r][nt] = (float)fv[r];
        }
        const size_t cb = (size_t)(n0 + wv * 16 + qd * 4) * KK;
        int id[4];
#pragma unroll
        for (int r = 0; r < 4; ++r) id[r] = cidx[cb + r * KK];   // ids k=0
#pragma unroll 1
        for (int k = 0; k < KK; ++k) {
            uint2 v[4][4];
#pragma unroll
            for (int r = 0; r < 4; ++r)
#pragma unroll
                for (int nt = 0; nt < 4; ++nt)
                    v[r][nt] = sprev[(size_t)id[r] * 64 + nt * 16 + lr];
            int idn[4];
            if (k + 1 < KK) {                                // prefetch ids k+1
#pragma unroll
                for (int r = 0; r < 4; ++r) idn[r] = cidx[cb + r * KK + k + 1];
            }
#pragma unroll
            for (int r = 0; r < 4; ++r)
#pragma unroll
                for (int nt = 0; nt < 4; ++nt) {
                    const float h = (float)(short)(v[r][nt].x & 0xFFFFu) * (1.f / 32767.f);
                    const float g = (float)((int)v[r][nt].x >> 16) * (1.f / 2048.f);
                    const float c = __uint_as_float(v[r][nt].y);
                    hs[r][nt] += h;
                    bfv[r][nt] = fmaf(sigm(wfx[r][nt] + g), c, bfv[r][nt]);
                }
            if (k + 1 < KK) {
#pragma unroll
                for (int r = 0; r < 4; ++r) id[r] = idn[r];
            }
        }
    }
    // ---- hsum -> LDS A-tile, split hi/lo bf16 (|hs|<=16 precision-critical)
#pragma unroll
    for (int r = 0; r < 4; ++r)
#pragma unroll
        for (int nt = 0; nt < 4; ++nt) {
            const int m = wv * 16 + qd * 4 + r, col = nt * 16 + lr;
            const unsigned short hi = f2bf(hs[r][nt]);
            Ah[m][col] = hi;
            AlHs[m][col] = f2bf(hs[r][nt] - bf2f(hi));
        }
    __syncthreads();
    short8 ah[2], al[2];
#pragma unroll
    for (int ks = 0; ks < 2; ++ks) {
        ah[ks] = *(const short8*)&Ah[wv * 16 + lr][ks * 32 + qd * 8];
        al[ks] = *(const short8*)&AlHs[wv * 16 + lr][ks * 32 + qd * 8];
    }
    // ---- iuo GEMM: acc = hsum @ U_iuo (split-bf16 A, fp32 acc), 12 out-tiles
    floatx4 acc[12];
#pragma unroll
    for (int nt = 0; nt < 12; ++nt) {
        floatx4 a = (floatx4){0.f, 0.f, 0.f, 0.f};
#pragma unroll
        for (int ks = 0; ks < 2; ++ks) {
            const short8 bu = *(const short8*)&Bi[nt * 16 + lr][ks * 32 + qd * 8];
            a = __builtin_amdgcn_mfma_f32_16x16x32_bf16(al[ks], bu, a, 0, 0, 0);
            a = __builtin_amdgcn_mfma_f32_16x16x32_bf16(ah[ks], bu, a, 0, 0, 0);
        }
        acc[nt] = a;
    }
    // ---- gate epilogue: i/u/o Wx tiles are dwordx2 fragment loads
    float nhv[4][4], ncv[4][4];
#pragma unroll
    for (int nt = 0; nt < 4; ++nt) {
        const int col = nt * 16 + lr;
        const half4v iv = *(const half4v*)&wbase[(4 + nt) * 256];
        const half4v uv = *(const half4v*)&wbase[(8 + nt) * 256];
        const half4v ov = *(const half4v*)&wbase[(12 + nt) * 256];
#pragma unroll
        for (int r = 0; r < 4; ++r) {
            const int node = n0 + wv * 16 + qd * 4 + r;
            const float ig = sigm(acc[nt][r] + (float)iv[r]);
            const float ug = ftanh(acc[4 + nt][r] + (float)uv[r]);
            const float og = sigm(acc[8 + nt][r] + (float)ov[r]);
            const float nc = fmaf(ig, ug, bfv[r][nt]);
            const float nh = og * ftanh(nc);
            nhv[nt][r] = nh;
            ncv[nt][r] = nc;
            if (last) {
                out[(size_t)node * 64 + col] = nh;
            } else {
                AlHs[wv * 16 + qd * 4 + r][col] = f2bf(nh);  // Al dead: restage nh
            }
        }
    }
    if (!last) {
        // ---- g = nh @ U_f (wave-private LDS tile; lgkmcnt covers the dep)
        short8 ag[2];
#pragma unroll
        for (int ks = 0; ks < 2; ++ks)
            ag[ks] = *(const short8*)&AlHs[wv * 16 + lr][ks * 32 + qd * 8];
        floatx4 g[4];
#pragma unroll
        for (int nt = 0; nt < 4; ++nt) {
            g[nt] = (floatx4){0.f, 0.f, 0.f, 0.f};
#pragma unroll
            for (int ks = 0; ks < 2; ++ks) {
                const short8 bfr = *(const short8*)&Bf[nt * 16 + lr][ks * 32 + qd * 8];
                g[nt] = __builtin_amdgcn_mfma_f32_16x16x32_bf16(ag[ks], bfr, g[nt], 0, 0, 0);
            }
        }
#pragma unroll
        for (int nt = 0; nt < 4; ++nt) {
#pragma unroll
            for (int r = 0; r < 4; ++r) {
                const int node = n0 + wv * 16 + qd * 4 + r;
                // |nh|<1 (o*tanh), |g|<=8 (64 * 1 * 0.125) -> int16 scales safe
                const int hq = (int)rintf(nhv[nt][r] * 32767.f);
                const int gq = (int)rintf(g[nt][r] * 2048.f);
                uint2 pw;
                pw.x = ((unsigned)hq & 0xFFFFu) | ((unsigned)gq << 16);
                pw.y = __float_as_uint(ncv[nt][r]);
                snext[(size_t)(node + 1) * 64 + nt * 16 + lr] = pw;
            }
        }
        if (blockIdx.x == 0 && tid < 64)
            snext[tid] = make_uint2(0u, 0u);   // zero init-state row
    }
}

extern "C" void kernel_launch(void* const* d_in, const int* in_sizes, int n_in,
                              void* d_out, int out_size, void* d_ws, size_t ws_size,
                              hipStream_t stream)
{
    const int*   labels = (const int*)d_in[0];    // [6, 32768]
    const int*   child  = (const int*)d_in[1];    // [6, 32768, 16]
    const float* E      = (const float*)d_in[2];  // [100000, 64]
    const float* W_w    = (const float*)d_in[3];  // [64, 256]
    const float* W_b    = (const float*)d_in[4];  // [256]
    const float* U_f    = (const float*)d_in[5];  // [64, 64]
    const float* U_iuo  = (const float*)d_in[6];  // [64, 192]
    float* out = (float*)d_out;

    // ws: s0,s1 = (NN+1)*512 B state ping-pong (16.8 MB each);
    //     WxF = 6 depths x NN*256 fp16 (fragment layout) = 100.7 MB.
    uint2* s0 = (uint2*)d_ws;
    uint2* s1 = s0 + (size_t)(NN + 1) * 64;
    _Float16* WxF = (_Float16*)(s1 + (size_t)(NN + 1) * 64);

    k0_all<<<6 * (NN / 64), 256, 0, stream>>>(labels, E, W_w, W_b, WxF);

    uint2* sp = s0;
    uint2* sn = s1;
    for (int d = 0; d < DD; ++d) {
        const int last = (d == DD - 1);
        kd_fused<<<NN / 64, 256, 0, stream>>>(
            child + (size_t)d * NN * KK, sp,
            WxF + (size_t)d * NN * 256,
            U_iuo, U_f, sn, out, d == 0, last);
        uint2* ts = sp; sp = sn; sn = ts;
    }
}

// Round 13
// 329.286 us; speedup vs baseline: 1.2410x; 1.0883x over previous
//
#include <hip/hip_runtime.h>

#define NN 32768
#define KK 16
#define DD 6
// State row per node-slot j: 384 B.
//   u32 words  [j*96 .. j*96+64):       hg = (int16)(h*32767) | (int16)(g*2048)<<16
//   f16 halves [j*192+128 .. j*192+192): c as fp16  (R6-proven: tanh saturation
//                                        shields fp16 c error; absmax 0.0117 there)
// Row 0 = all zero (child_idx==0 masking is free).
// WxF: fp16 pre-activations in MFMA C-FRAGMENT layout:
//   [dep][block b][wave wv][tile nt(16)][lane ln(64)][reg r(4)]

typedef short short8 __attribute__((ext_vector_type(8)));
typedef float floatx4 __attribute__((ext_vector_type(4)));
typedef _Float16 half4v __attribute__((ext_vector_type(4)));

__device__ __forceinline__ float sigm(float x) { return 1.0f / (1.0f + __expf(-x)); }
__device__ __forceinline__ float ftanh(float x) {
    float e = __expf(2.0f * x);
    return 1.0f - 2.0f / (e + 1.0f);
}
__device__ __forceinline__ unsigned short f2bf(float x) {   // RNE fp32->bf16
    union { float f; unsigned u; } v; v.f = x;
    unsigned r = v.u + 0x7FFF + ((v.u >> 16) & 1);
    return (unsigned short)(r >> 16);
}
__device__ __forceinline__ float bf2f(unsigned short h) {
    union { unsigned u; float f; } v; v.u = ((unsigned)h) << 16; return v.f;
}

// ---------------------------------------------------------------------------
// K0_ALL (MFMA): WxF[dep][n-block] = frag(E[labels] @ W_w + W_b), all 6 depths
// in one launch (R8/R10/R12-proven; fragment dwordx2 stores).
__global__ __launch_bounds__(256) void k0_all(
    const int* __restrict__ labels, const float* __restrict__ E,
    const float* __restrict__ W_w, const float* __restrict__ W_b,
    _Float16* __restrict__ WxF)
{
    __shared__ int labs[64];
    __shared__ __align__(16) unsigned short Ax[64][74];
    __shared__ __align__(16) unsigned short Bw[256][74];
    const int tid = threadIdx.x;
    const int blk = blockIdx.x & 511;
    const int dep = blockIdx.x >> 9;
    const int n0 = blk * 64;
    if (tid < 64) labs[tid] = labels[(size_t)dep * NN + n0 + tid];
    __syncthreads();
    {   // stage A: thread -> node m = tid>>2, 16 dims
        const int m = tid >> 2, q = tid & 3;
        const float4* e4 = (const float4*)(E + (size_t)labs[m] * 64 + q * 16);
#pragma unroll
        for (int i = 0; i < 4; ++i) {
            float4 v = e4[i];
            Ax[m][q * 16 + i * 4 + 0] = f2bf(v.x);
            Ax[m][q * 16 + i * 4 + 1] = f2bf(v.y);
            Ax[m][q * 16 + i * 4 + 2] = f2bf(v.z);
            Ax[m][q * 16 + i * 4 + 3] = f2bf(v.w);
        }
    }
    {   // stage B transposed: thread = col, coalesced global reads per k
        const int c = tid;
#pragma unroll 4
        for (int k = 0; k < 64; ++k) Bw[c][k] = f2bf(W_w[k * 256 + c]);
    }
    __syncthreads();
    const int ln = tid & 63, wv = tid >> 6;
    const int lr = ln & 15, qd = ln >> 4;
    short8 af[2];
#pragma unroll
    for (int ks = 0; ks < 2; ++ks)
        af[ks] = *(const short8*)&Ax[wv * 16 + lr][ks * 32 + qd * 8];
    floatx4 acc[16];
#pragma unroll
    for (int nt = 0; nt < 16; ++nt) acc[nt] = (floatx4){0.f, 0.f, 0.f, 0.f};
#pragma unroll
    for (int nt = 0; nt < 16; ++nt) {
#pragma unroll
        for (int ks = 0; ks < 2; ++ks) {
            short8 bw = *(const short8*)&Bw[nt * 16 + lr][ks * 32 + qd * 8];
            acc[nt] = __builtin_amdgcn_mfma_f32_16x16x32_bf16(af[ks], bw, acc[nt], 0, 0, 0);
        }
    }
    _Float16* __restrict__ base =
        WxF + ((size_t)(dep * 512 + blk) * 4 + wv) * 16 * 256 + (size_t)ln * 4;
#pragma unroll
    for (int nt = 0; nt < 16; ++nt) {
        const float bb = W_b[nt * 16 + lr];
        half4v hv;
#pragma unroll
        for (int r = 0; r < 4; ++r) hv[r] = (_Float16)(acc[nt][r] + bb);
        *(half4v*)&base[nt * 256] = hv;
    }
}

// ---------------------------------------------------------------------------
// KD: R12 structure (simple gather + 1-deep id prefetch, fragment Wx loads),
// with 384-B state rows: per child 1 u32 hg load + 1 u16 c load. Fetch-BW
// bound at ~3.2 TB/s random-gather fabric rate -> time scales with lines
// touched (8 -> 6 per row).
__global__ __launch_bounds__(256) void kd_fused(
    const int* __restrict__ cidx, const unsigned* __restrict__ sprev,
    const _Float16* __restrict__ Wx, const float* __restrict__ U_iuo,
    const float* __restrict__ U_f, unsigned* __restrict__ snext,
    float* __restrict__ out, int first, int last)
{
    __shared__ __align__(16) unsigned short Bi[192][68];   // U_iuo^T [c][k]
    __shared__ __align__(16) unsigned short Bf[64][68];    // U_f^T   [c][k]
    __shared__ __align__(16) unsigned short Ah[64][68];    // hsum hi
    __shared__ __align__(16) unsigned short AlHs[64][68];  // hsum lo, later nh
    const int tid = threadIdx.x;
    const int n0 = blockIdx.x * 64;
    if (tid < 192) {
        const int c = tid;
#pragma unroll 4
        for (int k = 0; k < 64; ++k) Bi[c][k] = f2bf(U_iuo[k * 192 + c]);
    } else {
        const int c = tid - 192;
#pragma unroll 4
        for (int k = 0; k < 64; ++k) Bf[c][k] = f2bf(U_f[k * 64 + c]);
    }
    const int ln = tid & 63, wv = tid >> 6;
    const int lr = ln & 15, qd = ln >> 4;
    const _Float16* __restrict__ wbase =
        Wx + ((size_t)blockIdx.x * 4 + wv) * 16 * 256 + (size_t)ln * 4;

    // ---- gather phase: hs/bf in C-layout registers, id-prefetched
    float hs[4][4] = {{0.f}}, bfv[4][4] = {{0.f}};
    if (!first) {
        float wfx[4][4];
#pragma unroll
        for (int nt = 0; nt < 4; ++nt) {                     // f tiles 0..3
            const half4v fv = *(const half4v*)&wbase[nt * 256];
#pragma unroll
            for (int r = 0; r < 4; ++r) wfx[r][nt] = (float)fv[r];
        }
        const _Float16* __restrict__ ch = (const _Float16*)sprev;
        const size_t cb = (size_t)(n0 + wv * 16 + qd * 4) * KK;
        int id[4];
#pragma unroll
        for (int r = 0; r < 4; ++r) id[r] = cidx[cb + r * KK];   // ids k=0
#pragma unroll 1
        for (int k = 0; k < KK; ++k) {
            unsigned hg[4][4];
            _Float16 cv[4][4];
#pragma unroll
            for (int r = 0; r < 4; ++r)
#pragma unroll
                for (int nt = 0; nt < 4; ++nt)
                    hg[r][nt] = sprev[(size_t)id[r] * 96 + nt * 16 + lr];
#pragma unroll
            for (int r = 0; r < 4; ++r)
#pragma unroll
                for (int nt = 0; nt < 4; ++nt)
                    cv[r][nt] = ch[(size_t)id[r] * 192 + 128 + nt * 16 + lr];
            int idn[4];
            if (k + 1 < KK) {                                // prefetch ids k+1
#pragma unroll
                for (int r = 0; r < 4; ++r) idn[r] = cidx[cb + r * KK + k + 1];
            }
#pragma unroll
            for (int r = 0; r < 4; ++r)
#pragma unroll
                for (int nt = 0; nt < 4; ++nt) {
                    const float h = (float)(short)(hg[r][nt] & 0xFFFFu) * (1.f / 32767.f);
                    const float g = (float)((int)hg[r][nt] >> 16) * (1.f / 2048.f);
                    hs[r][nt] += h;
                    bfv[r][nt] = fmaf(sigm(wfx[r][nt] + g), (float)cv[r][nt], bfv[r][nt]);
                }
            if (k + 1 < KK) {
#pragma unroll
                for (int r = 0; r < 4; ++r) id[r] = idn[r];
            }
        }
    }
    // ---- hsum -> LDS A-tile, split hi/lo bf16 (|hs|<=16 precision-critical)
#pragma unroll
    for (int r = 0; r < 4; ++r)
#pragma unroll
        for (int nt = 0; nt < 4; ++nt) {
            const int m = wv * 16 + qd * 4 + r, col = nt * 16 + lr;
            const unsigned short hi = f2bf(hs[r][nt]);
            Ah[m][col] = hi;
            AlHs[m][col] = f2bf(hs[r][nt] - bf2f(hi));
        }
    __syncthreads();
    short8 ah[2], al[2];
#pragma unroll
    for (int ks = 0; ks < 2; ++ks) {
        ah[ks] = *(const short8*)&Ah[wv * 16 + lr][ks * 32 + qd * 8];
        al[ks] = *(const short8*)&AlHs[wv * 16 + lr][ks * 32 + qd * 8];
    }
    // ---- iuo GEMM: acc = hsum @ U_iuo (split-bf16 A, fp32 acc), 12 out-tiles
    floatx4 acc[12];
#pragma unroll
    for (int nt = 0; nt < 12; ++nt) {
        floatx4 a = (floatx4){0.f, 0.f, 0.f, 0.f};
#pragma unroll
        for (int ks = 0; ks < 2; ++ks) {
            const short8 bu = *(const short8*)&Bi[nt * 16 + lr][ks * 32 + qd * 8];
            a = __builtin_amdgcn_mfma_f32_16x16x32_bf16(al[ks], bu, a, 0, 0, 0);
            a = __builtin_amdgcn_mfma_f32_16x16x32_bf16(ah[ks], bu, a, 0, 0, 0);
        }
        acc[nt] = a;
    }
    // ---- gate epilogue: i/u/o Wx tiles are dwordx2 fragment loads
    float nhv[4][4], ncv[4][4];
#pragma unroll
    for (int nt = 0; nt < 4; ++nt) {
        const int col = nt * 16 + lr;
        const half4v iv = *(const half4v*)&wbase[(4 + nt) * 256];
        const half4v uv = *(const half4v*)&wbase[(8 + nt) * 256];
        const half4v ov = *(const half4v*)&wbase[(12 + nt) * 256];
#pragma unroll
        for (int r = 0; r < 4; ++r) {
            const int node = n0 + wv * 16 + qd * 4 + r;
            const float ig = sigm(acc[nt][r] + (float)iv[r]);
            const float ug = ftanh(acc[4 + nt][r] + (float)uv[r]);
            const float og = sigm(acc[8 + nt][r] + (float)ov[r]);
            const float nc = fmaf(ig, ug, bfv[r][nt]);
            const float nh = og * ftanh(nc);
            nhv[nt][r] = nh;
            ncv[nt][r] = nc;
            if (last) {
                out[(size_t)node * 64 + col] = nh;
            } else {
                AlHs[wv * 16 + qd * 4 + r][col] = f2bf(nh);  // Al dead: restage nh
            }
        }
    }
    if (!last) {
        // ---- g = nh @ U_f (wave-private LDS tile; lgkmcnt covers the dep)
        short8 ag[2];
#pragma unroll
        for (int ks = 0; ks < 2; ++ks)
            ag[ks] = *(const short8*)&AlHs[wv * 16 + lr][ks * 32 + qd * 8];
        floatx4 g[4];
#pragma unroll
        for (int nt = 0; nt < 4; ++nt) {
            g[nt] = (floatx4){0.f, 0.f, 0.f, 0.f};
#pragma unroll
            for (int ks = 0; ks < 2; ++ks) {
                const short8 bfr = *(const short8*)&Bf[nt * 16 + lr][ks * 32 + qd * 8];
                g[nt] = __builtin_amdgcn_mfma_f32_16x16x32_bf16(ag[ks], bfr, g[nt], 0, 0, 0);
            }
        }
        _Float16* __restrict__ dh = (_Float16*)snext;
#pragma unroll
        for (int nt = 0; nt < 4; ++nt) {
#pragma unroll
            for (int r = 0; r < 4; ++r) {
                const int node = n0 + wv * 16 + qd * 4 + r;
                // |nh|<1 (o*tanh), |g|<=8 (64 * 1 * 0.125) -> int16 scales safe
                const int hq = (int)rintf(nhv[nt][r] * 32767.f);
                const int gq = (int)rintf(g[nt][r] * 2048.f);
                snext[(size_t)(node + 1) * 96 + nt * 16 + lr] =
                    ((unsigned)hq & 0xFFFFu) | ((unsigned)gq << 16);
                dh[(size_t)(node + 1) * 192 + 128 + nt * 16 + lr] =
                    (_Float16)ncv[nt][r];
            }
        }
        if (blockIdx.x == 0 && tid < 96)
            snext[tid] = 0u;               // zero init-state row (h,g,c = 0)
    }
}

extern "C" void kernel_launch(void* const* d_in, const int* in_sizes, int n_in,
                              void* d_out, int out_size, void* d_ws, size_t ws_size,
                              hipStream_t stream)
{
    const int*   labels = (const int*)d_in[0];    // [6, 32768]
    const int*   child  = (const int*)d_in[1];    // [6, 32768, 16]
    const float* E      = (const float*)d_in[2];  // [100000, 64]
    const float* W_w    = (const float*)d_in[3];  // [64, 256]
    const float* W_b    = (const float*)d_in[4];  // [256]
    const float* U_f    = (const float*)d_in[5];  // [64, 64]
    const float* U_iuo  = (const float*)d_in[6];  // [64, 192]
    float* out = (float*)d_out;

    // ws: s0,s1 = (NN+1)*384 B state ping-pong (12.6 MB each);
    //     WxF = 6 depths x NN*256 fp16 (fragment layout) = 100.7 MB.
    unsigned* s0 = (unsigned*)d_ws;
    unsigned* s1 = s0 + (size_t)(NN + 1) * 96;
    _Float16* WxF = (_Float16*)(s1 + (size_t)(NN + 1) * 96);

    k0_all<<<6 * (NN / 64), 256, 0, stream>>>(labels, E, W_w, W_b, WxF);

    unsigned* sp = s0;
    unsigned* sn = s1;
    for (int d = 0; d < DD; ++d) {
        const int last = (d == DD - 1);
        kd_fused<<<NN / 64, 256, 0, stream>>>(
            child + (size_t)d * NN * KK, sp,
            WxF + (size_t)d * NN * 256,
            U_iuo, U_f, sn, out, d == 0, last);
        unsigned* ts = sp; sp = sn; sn = ts;
    }
}